// Round 2
// baseline (1343.710 us; speedup 1.0000x reference)
//
#include <hip/hip_runtime.h>
#include <math.h>

#define HNUM 16
#define DH 64
#define NSEQ 1024
#define BATCH 2
#define DMODEL 1024
#define SCALE 0.125f
#define EPS 1e-6f
#define NUM_ITER 4

// ---------------------------------------------------------------------------
// GEMM: C[M,Nc] = A[M,K] @ B[Nc,K]^T   (both row-major; B accessed B[n][k])
// 128x128 tile, BK=16, 256 threads, 8x8 per thread, fp32.
// ---------------------------------------------------------------------------
__global__ __launch_bounds__(256) void gemm_nt_f32(const float* __restrict__ A,
                                                   const float* __restrict__ B,
                                                   float* __restrict__ C,
                                                   int M, int Nc, int K) {
    __shared__ float As[16][132];
    __shared__ float Bs[16][132];
    const int tid = threadIdx.x;
    const int tx = tid & 15, ty = tid >> 4;
    const int m0 = blockIdx.y * 128, n0 = blockIdx.x * 128;

    float acc[8][8];
#pragma unroll
    for (int i = 0; i < 8; ++i)
#pragma unroll
        for (int j = 0; j < 8; ++j) acc[i][j] = 0.f;

    for (int k0 = 0; k0 < K; k0 += 16) {
#pragma unroll
        for (int L = 0; L < 2; ++L) {
            const int idx = tid + L * 256;
            const int r  = idx >> 2;
            const int c4 = (idx & 3) << 2;
            const float4 av = *reinterpret_cast<const float4*>(
                &A[(size_t)(m0 + r) * K + k0 + c4]);
            As[c4 + 0][r] = av.x; As[c4 + 1][r] = av.y;
            As[c4 + 2][r] = av.z; As[c4 + 3][r] = av.w;
            const float4 bv = *reinterpret_cast<const float4*>(
                &B[(size_t)(n0 + r) * K + k0 + c4]);
            Bs[c4 + 0][r] = bv.x; Bs[c4 + 1][r] = bv.y;
            Bs[c4 + 2][r] = bv.z; Bs[c4 + 3][r] = bv.w;
        }
        __syncthreads();
#pragma unroll
        for (int kk = 0; kk < 16; ++kk) {
            float a[8], b[8];
#pragma unroll
            for (int i = 0; i < 8; ++i) a[i] = As[kk][ty * 8 + i];
#pragma unroll
            for (int j = 0; j < 8; ++j) b[j] = Bs[kk][tx * 8 + j];
#pragma unroll
            for (int i = 0; i < 8; ++i)
#pragma unroll
                for (int j = 0; j < 8; ++j)
                    acc[i][j] = fmaf(a[i], b[j], acc[i][j]);
        }
        __syncthreads();
    }

#pragma unroll
    for (int i = 0; i < 8; ++i) {
#pragma unroll
        for (int j = 0; j < 8; ++j) {
            C[(size_t)(m0 + ty * 8 + i) * Nc + n0 + tx * 8 + j] = acc[i][j];
        }
    }
}

// ---------------------------------------------------------------------------
// Stieltjes attention, one wave per query row.
// qkv: [B*N, 3*DMODEL] rows laid out [3][H][DH].  o: [B,N,H,DH].
// Lane l owns scores j = l + 64c.  PV: lane accumulates its own rows'
// contribution to ALL 64 dims, then 6-step recursive-halving lane reduce
// (all register indices compile-time -> no scratch).
// ---------------------------------------------------------------------------
__global__ __launch_bounds__(256) void stieltjes_attn(const float* __restrict__ qkv,
                                                      float* __restrict__ o) {
    const int wid  = threadIdx.x >> 6;
    const int lane = threadIdx.x & 63;
    const int row  = blockIdx.x * 4 + wid;      // 0 .. B*H*N-1
    const int i = row & (NSEQ - 1);
    const int h = (row >> 10) & (HNUM - 1);
    const int b = row >> 14;

    const size_t rs = 3 * DMODEL;
    const float* qptr  = qkv + (size_t)(b * NSEQ + i) * rs + h * DH;
    const float* kbase = qkv + (size_t)(b * NSEQ) * rs + DMODEL + h * DH;
    const float* vbase = kbase + DMODEL;

    __shared__ __align__(16) float qs[4][DH];
    qs[wid][lane] = qptr[lane];
    __syncthreads();
    const float4* q4 = reinterpret_cast<const float4*>(qs[wid]);

    // ---- scores ----
    float s[16];
#pragma unroll
    for (int c = 0; c < 16; ++c) {
        const int j = lane + (c << 6);
        float acc = -1e30f;
        if (j <= i) {
            const float4* krow = reinterpret_cast<const float4*>(kbase + (size_t)j * rs);
            float a = 0.f;
#pragma unroll
            for (int d4 = 0; d4 < 16; ++d4) {
                const float4 kv = krow[d4];
                const float4 qv = q4[d4];
                a = fmaf(qv.x, kv.x, a); a = fmaf(qv.y, kv.y, a);
                a = fmaf(qv.z, kv.z, a); a = fmaf(qv.w, kv.w, a);
            }
            acc = a * SCALE;
        }
        s[c] = acc;
    }

    // ---- lambda init ----
    float m = -1e30f;
#pragma unroll
    for (int c = 0; c < 16; ++c) m = fmaxf(m, s[c]);
#pragma unroll
    for (int off = 32; off; off >>= 1) m = fmaxf(m, __shfl_xor(m, off));
    float lam = m + 1.0f;

    // ---- Newton ----
    for (int it = 0; it < NUM_ITER; ++it) {
        float f = 0.f, fp = 0.f;
#pragma unroll
        for (int c = 0; c < 16; ++c) {
            const int j = lane + (c << 6);
            if (j <= i) {
                const float d   = fmaxf(lam - s[c], EPS);
                const float inv = __builtin_amdgcn_rcpf(d);
                f  += inv;
                fp  = fmaf(inv, inv, fp);
            }
        }
#pragma unroll
        for (int off = 32; off; off >>= 1) {
            f  += __shfl_xor(f, off);
            fp += __shfl_xor(fp, off);
        }
        lam += (f - 1.0f) / fp;
    }

    // ---- final weights + normalizer ----
    float w[16];
    float sw = 0.f;
#pragma unroll
    for (int c = 0; c < 16; ++c) {
        const int j = lane + (c << 6);
        float ww = 0.f;
        if (j <= i) {
            const float d = fmaxf(lam - s[c], EPS);
            ww = __builtin_amdgcn_rcpf(d);
        }
        w[c] = ww;
        sw += ww;
    }
#pragma unroll
    for (int off = 32; off; off >>= 1) sw += __shfl_xor(sw, off);
    const float invsw = __builtin_amdgcn_rcpf(sw);

    // ---- PV: per-lane accumulate own rows into all 64 dims ----
    float acc[64];
#pragma unroll
    for (int d = 0; d < 64; ++d) acc[d] = 0.f;

#pragma unroll
    for (int c = 0; c < 16; ++c) {
        const int j0 = c << 6;
        if (j0 <= i) {                           // wave-uniform guard
            const int j = lane + j0;             // w[c]==0 when j>i
            const float4* vrow = reinterpret_cast<const float4*>(vbase + (size_t)j * rs);
            const float ww = w[c];
#pragma unroll
            for (int d4 = 0; d4 < 16; ++d4) {
                const float4 vv = vrow[d4];
                acc[d4 * 4 + 0] = fmaf(ww, vv.x, acc[d4 * 4 + 0]);
                acc[d4 * 4 + 1] = fmaf(ww, vv.y, acc[d4 * 4 + 1]);
                acc[d4 * 4 + 2] = fmaf(ww, vv.z, acc[d4 * 4 + 2]);
                acc[d4 * 4 + 3] = fmaf(ww, vv.w, acc[d4 * 4 + 3]);
            }
        }
    }

    // ---- 6-step recursive-halving reduce: lane l ends with dim l ----
#pragma unroll
    for (int step = 0; step < 6; ++step) {
        const int mS = 32 >> step;               // 32,16,8,4,2,1
        const bool hi = (lane & mS) != 0;
#pragma unroll
        for (int t = 0; t < 32; ++t) {
            if (t < mS) {
                const float send = hi ? acc[t] : acc[t + mS];
                const float recv = __shfl_xor(send, mS);
                const float keep = hi ? acc[t + mS] : acc[t];
                acc[t] = keep + recv;
            }
        }
    }

    o[((size_t)(b * NSEQ + i) * HNUM + h) * DH + lane] = acc[0] * invsw;
}

extern "C" void kernel_launch(void* const* d_in, const int* in_sizes, int n_in,
                              void* d_out, int out_size, void* d_ws, size_t ws_size,
                              hipStream_t stream) {
    const float* x    = (const float*)d_in[0];   // [B,N,D]
    const float* Wqkv = (const float*)d_in[1];   // [3D, D]
    const float* Wo   = (const float*)d_in[2];   // [D, D]
    float* out = (float*)d_out;                  // [B,N,D]

    float* qkv = (float*)d_ws;                               // [2048, 3072]
    float* o   = qkv + (size_t)(BATCH * NSEQ) * 3 * DMODEL;  // [2048, 1024]

    const int M = BATCH * NSEQ;                  // 2048

    dim3 blk(256);
    dim3 g1(3 * DMODEL / 128, M / 128);
    gemm_nt_f32<<<g1, blk, 0, stream>>>(x, Wqkv, qkv, M, 3 * DMODEL, DMODEL);

    dim3 ga(BATCH * HNUM * NSEQ / 4);
    stieltjes_attn<<<ga, blk, 0, stream>>>(qkv, o);

    dim3 g2(DMODEL / 128, M / 128);
    gemm_nt_f32<<<g2, blk, 0, stream>>>(o, Wo, out, M, DMODEL, DMODEL);
}

// Round 3
// 982.354 us; speedup vs baseline: 1.3678x; 1.3678x over previous
//
#include <hip/hip_runtime.h>
#include <math.h>

#define HNUM 16
#define DH 64
#define NSEQ 1024
#define BATCH 2
#define DMODEL 1024
#define SCALE 0.125f
#define EPS 1e-6f
#define NUM_ITER 4

// ---------------------------------------------------------------------------
// GEMM: C[M,Nc] = A[M,K] @ B[Nc,K]^T   (row-major; B accessed B[n][k])
// 128x128 tile, BK=16, 256 threads, 8x8 per thread, fp32.
// ---------------------------------------------------------------------------
__global__ __launch_bounds__(256) void gemm_nt_f32(const float* __restrict__ A,
                                                   const float* __restrict__ B,
                                                   float* __restrict__ C,
                                                   int M, int Nc, int K) {
    __shared__ float As[16][132];
    __shared__ float Bs[16][132];
    const int tid = threadIdx.x;
    const int tx = tid & 15, ty = tid >> 4;
    const int m0 = blockIdx.y * 128, n0 = blockIdx.x * 128;

    float acc[8][8];
#pragma unroll
    for (int i = 0; i < 8; ++i)
#pragma unroll
        for (int j = 0; j < 8; ++j) acc[i][j] = 0.f;

    for (int k0 = 0; k0 < K; k0 += 16) {
#pragma unroll
        for (int L = 0; L < 2; ++L) {
            const int idx = tid + L * 256;
            const int r  = idx >> 2;
            const int c4 = (idx & 3) << 2;
            const float4 av = *reinterpret_cast<const float4*>(
                &A[(size_t)(m0 + r) * K + k0 + c4]);
            As[c4 + 0][r] = av.x; As[c4 + 1][r] = av.y;
            As[c4 + 2][r] = av.z; As[c4 + 3][r] = av.w;
            const float4 bv = *reinterpret_cast<const float4*>(
                &B[(size_t)(n0 + r) * K + k0 + c4]);
            Bs[c4 + 0][r] = bv.x; Bs[c4 + 1][r] = bv.y;
            Bs[c4 + 2][r] = bv.z; Bs[c4 + 3][r] = bv.w;
        }
        __syncthreads();
#pragma unroll
        for (int kk = 0; kk < 16; ++kk) {
            float a[8], b[8];
#pragma unroll
            for (int i = 0; i < 8; ++i) a[i] = As[kk][ty * 8 + i];
#pragma unroll
            for (int j = 0; j < 8; ++j) b[j] = Bs[kk][tx * 8 + j];
#pragma unroll
            for (int i = 0; i < 8; ++i)
#pragma unroll
                for (int j = 0; j < 8; ++j)
                    acc[i][j] = fmaf(a[i], b[j], acc[i][j]);
        }
        __syncthreads();
    }

#pragma unroll
    for (int i = 0; i < 8; ++i) {
#pragma unroll
        for (int j = 0; j < 8; ++j) {
            C[(size_t)(m0 + ty * 8 + i) * Nc + n0 + tx * 8 + j] = acc[i][j];
        }
    }
}

// ---------------------------------------------------------------------------
// Stieltjes attention, one wave per query row.
// qkv: [B*N, 3*DMODEL] rows laid out [3][H][DH].  o: [B,N,H,DH].
// Scores/Newton: lane l owns j = l + 64c (registers).
// PV: weights staged to a per-wave LDS row (broadcast reads), lane l owns
// output dim l, 8-way unrolled coalesced V loads, 4 partial accumulators.
// ---------------------------------------------------------------------------
__global__ __launch_bounds__(256) void stieltjes_attn(const float* __restrict__ qkv,
                                                      float* __restrict__ o) {
    const int wid  = threadIdx.x >> 6;
    const int lane = threadIdx.x & 63;
    const int row  = blockIdx.x * 4 + wid;      // 0 .. B*H*N-1
    const int i = row & (NSEQ - 1);
    const int h = (row >> 10) & (HNUM - 1);
    const int b = row >> 14;

    const size_t rs = 3 * DMODEL;
    const float* qptr  = qkv + (size_t)(b * NSEQ + i) * rs + h * DH;
    const float* kbase = qkv + (size_t)(b * NSEQ) * rs + DMODEL + h * DH;
    const float* vbase = kbase + DMODEL;

    __shared__ __align__(16) float qs[4][DH];
    __shared__ __align__(16) float w_lds[4][NSEQ];   // 16 KB, per-wave private rows
    qs[wid][lane] = qptr[lane];
    __syncthreads();
    const float4* q4 = reinterpret_cast<const float4*>(qs[wid]);

    // ---- scores s_j = (q . k_j) * SCALE ----
    float s[16];
#pragma unroll
    for (int c = 0; c < 16; ++c) {
        const int j = lane + (c << 6);
        float acc = -1e30f;
        if (j <= i) {
            const float4* krow = reinterpret_cast<const float4*>(kbase + (size_t)j * rs);
            float a = 0.f;
#pragma unroll
            for (int d4 = 0; d4 < 16; ++d4) {
                const float4 kv = krow[d4];
                const float4 qv = q4[d4];
                a = fmaf(qv.x, kv.x, a); a = fmaf(qv.y, kv.y, a);
                a = fmaf(qv.z, kv.z, a); a = fmaf(qv.w, kv.w, a);
            }
            acc = a * SCALE;
        }
        s[c] = acc;
    }

    // ---- lambda init ----
    float m = -1e30f;
#pragma unroll
    for (int c = 0; c < 16; ++c) m = fmaxf(m, s[c]);
#pragma unroll
    for (int off = 32; off; off >>= 1) m = fmaxf(m, __shfl_xor(m, off));
    float lam = m + 1.0f;

    // ---- Newton: solve sum 1/(lam - s_j) = 1 ----
    for (int it = 0; it < NUM_ITER; ++it) {
        float f = 0.f, fp = 0.f;
#pragma unroll
        for (int c = 0; c < 16; ++c) {
            const int j = lane + (c << 6);
            if (j <= i) {
                const float d   = fmaxf(lam - s[c], EPS);
                const float inv = __builtin_amdgcn_rcpf(d);
                f  += inv;
                fp  = fmaf(inv, inv, fp);
            }
        }
#pragma unroll
        for (int off = 32; off; off >>= 1) {
            f  += __shfl_xor(f, off);
            fp += __shfl_xor(fp, off);
        }
        lam += (f - 1.0f) / fp;
    }

    // ---- final weights + normalizer ----
    float w[16];
    float sw = 0.f;
#pragma unroll
    for (int c = 0; c < 16; ++c) {
        const int j = lane + (c << 6);
        float ww = 0.f;
        if (j <= i) {
            const float d = fmaxf(lam - s[c], EPS);
            ww = __builtin_amdgcn_rcpf(d);
        }
        w[c] = ww;
        sw += ww;
    }
#pragma unroll
    for (int off = 32; off; off >>= 1) sw += __shfl_xor(sw, off);
    const float invsw = __builtin_amdgcn_rcpf(sw);

    // ---- stage normalized weights to this wave's private LDS row ----
#pragma unroll
    for (int c = 0; c < 16; ++c) {
        w_lds[wid][lane + (c << 6)] = w[c] * invsw;   // conflict-free, wave-sync
    }
    // same-wave LDS RAW: compiler inserts lgkmcnt wait; no barrier needed
    // (each wave touches only w_lds[wid]).

    // ---- PV: lane owns dim=lane; broadcast weight reads from LDS ----
    const float* __restrict__ vcol = vbase + lane;
    const float* __restrict__ wrow = w_lds[wid];
    const int nj = i + 1;
    float a0 = 0.f, a1 = 0.f, a2 = 0.f, a3 = 0.f;
    int j = 0;
    for (; j + 8 <= nj; j += 8) {
        const float4 wa = *reinterpret_cast<const float4*>(&wrow[j]);
        const float4 wb = *reinterpret_cast<const float4*>(&wrow[j + 4]);
        const float v0 = vcol[(size_t)(j + 0) * rs];
        const float v1 = vcol[(size_t)(j + 1) * rs];
        const float v2 = vcol[(size_t)(j + 2) * rs];
        const float v3 = vcol[(size_t)(j + 3) * rs];
        const float v4 = vcol[(size_t)(j + 4) * rs];
        const float v5 = vcol[(size_t)(j + 5) * rs];
        const float v6 = vcol[(size_t)(j + 6) * rs];
        const float v7 = vcol[(size_t)(j + 7) * rs];
        a0 = fmaf(wa.x, v0, a0);
        a1 = fmaf(wa.y, v1, a1);
        a2 = fmaf(wa.z, v2, a2);
        a3 = fmaf(wa.w, v3, a3);
        a0 = fmaf(wb.x, v4, a0);
        a1 = fmaf(wb.y, v5, a1);
        a2 = fmaf(wb.z, v6, a2);
        a3 = fmaf(wb.w, v7, a3);
    }
    for (; j < nj; ++j) {
        a0 = fmaf(wrow[j], vcol[(size_t)j * rs], a0);
    }

    o[((size_t)(b * NSEQ + i) * HNUM + h) * DH + lane] = (a0 + a1) + (a2 + a3);
}

extern "C" void kernel_launch(void* const* d_in, const int* in_sizes, int n_in,
                              void* d_out, int out_size, void* d_ws, size_t ws_size,
                              hipStream_t stream) {
    const float* x    = (const float*)d_in[0];   // [B,N,D]
    const float* Wqkv = (const float*)d_in[1];   // [3D, D]
    const float* Wo   = (const float*)d_in[2];   // [D, D]
    float* out = (float*)d_out;                  // [B,N,D]

    float* qkv = (float*)d_ws;                               // [2048, 3072]
    float* o   = qkv + (size_t)(BATCH * NSEQ) * 3 * DMODEL;  // [2048, 1024]

    const int M = BATCH * NSEQ;                  // 2048

    dim3 blk(256);
    dim3 g1(3 * DMODEL / 128, M / 128);
    gemm_nt_f32<<<g1, blk, 0, stream>>>(x, Wqkv, qkv, M, 3 * DMODEL, DMODEL);

    dim3 ga(BATCH * HNUM * NSEQ / 4);
    stieltjes_attn<<<ga, blk, 0, stream>>>(qkv, o);

    dim3 g2(DMODEL / 128, M / 128);
    gemm_nt_f32<<<g2, blk, 0, stream>>>(o, Wo, out, M, DMODEL, DMODEL);
}